// Round 10
// baseline (298.993 us; speedup 1.0000x reference)
//
#include <hip/hip_runtime.h>
#include <cstdint>

#define S_LEN 2048
#define D_MODEL 1024
#define NH 16
#define HDIM 64
#define BATCH 4

typedef __attribute__((ext_vector_type(8))) __bf16 bfrag;   // 8 bf16 = 4 VGPR
typedef __attribute__((ext_vector_type(4))) float ffrag;    // 4 f32 acc

__device__ __forceinline__ unsigned short f2bf(float f) {
    union { float f; uint32_t u; } v; v.f = f;
    uint32_t u = v.u;
    u += 0x7fff + ((u >> 16) & 1);   // round-to-nearest-even
    return (unsigned short)(u >> 16);
}

__device__ __forceinline__ bfrag ld_frag(const unsigned short* p) {
    union { uint4 u; bfrag b; } x;
    x.u = *(const uint4*)p;
    return x.b;
}

__device__ __forceinline__ float fast_exp2(float x) {
#if __has_builtin(__builtin_amdgcn_exp2f)
    return __builtin_amdgcn_exp2f(x);
#else
    return __expf(x * 0.6931471805599453f);
#endif
}

// pack two f32 -> packed bf16x2 (round-half-up), 3 VALU inst
__device__ __forceinline__ uint32_t pack_bf16(float a, float b) {
    union { float f; uint32_t u; } x, y; x.f = a; y.f = b;
    return __builtin_amdgcn_perm(y.u + 0x8000u, x.u + 0x8000u, 0x07060302u);
}

__device__ __forceinline__ void g2l16(const unsigned short* g, unsigned short* l) {
    __builtin_amdgcn_global_load_lds(
        (const __attribute__((address_space(1))) void*)g,
        (__attribute__((address_space(3))) void*)l, 16, 0, 0);
}

// ---------------- cast x (fp32 -> bf16), 8 elems/thread ----------------
__global__ __launch_bounds__(256) void cast_x_kernel(const float* __restrict__ x,
                                                     unsigned short* __restrict__ xb,
                                                     int n8) {
    int i = blockIdx.x * 256 + threadIdx.x;
    if (i >= n8) return;
    const float4* p = (const float4*)x + (size_t)i * 2;
    float4 a = p[0], b = p[1];
    union { unsigned short u[8]; uint4 v; } o;
    o.u[0]=f2bf(a.x); o.u[1]=f2bf(a.y); o.u[2]=f2bf(a.z); o.u[3]=f2bf(a.w);
    o.u[4]=f2bf(b.x); o.u[5]=f2bf(b.y); o.u[6]=f2bf(b.z); o.u[7]=f2bf(b.w);
    ((uint4*)xb)[i] = o.v;
}

// ------------- cast + transpose weights: Wt[mat][n][k] = W[k][n] -------------
__global__ __launch_bounds__(256) void transpose_w_kernel(const float* __restrict__ w0,
                                                          const float* __restrict__ w1,
                                                          const float* __restrict__ w2,
                                                          const float* __restrict__ w3,
                                                          unsigned short* __restrict__ wt) {
    __shared__ float tile[32][33];
    int mat = blockIdx.z;
    const float* w = (mat == 0) ? w0 : (mat == 1) ? w1 : (mat == 2) ? w2 : w3;
    int n0 = blockIdx.x * 32, k0 = blockIdx.y * 32;
    int tx = threadIdx.x, ty = threadIdx.y;  // 32 x 8
    for (int i = 0; i < 32; i += 8)
        tile[ty + i][tx] = w[(size_t)(k0 + ty + i) * D_MODEL + n0 + tx];
    __syncthreads();
    unsigned short* o = wt + (size_t)mat * D_MODEL * D_MODEL;
    for (int i = 0; i < 32; i += 8)
        o[(size_t)(n0 + ty + i) * D_MODEL + (k0 + tx)] = f2bf(tile[tx][ty + i]);
}

// ------------- V transpose: Vb[bh][s][d] -> Vtb[bh][d][s] (bf16) -------------
// (verified correct in round 4)
__global__ __launch_bounds__(256) void transpose_v_kernel(const unsigned short* __restrict__ Vb,
                                                          unsigned short* __restrict__ Vtb) {
    __shared__ unsigned short tile[64][72];
    int st = blockIdx.x;   // s-tile of 64
    int bh = blockIdx.y;
    int t = threadIdx.x;
    int sl = t >> 2, dc = (t & 3) * 16;
    const unsigned short* src = Vb + ((size_t)bh * S_LEN + st * 64 + sl) * HDIM + dc;
    *(uint4*)&tile[sl][dc]     = *(const uint4*)(src);
    *(uint4*)&tile[sl][dc + 8] = *(const uint4*)(src + 8);
    __syncthreads();
    int d = t >> 2, sc = (t & 3) * 16;
    union { unsigned short u[16]; uint4 v[2]; } o;
#pragma unroll
    for (int i = 0; i < 16; i++) o.u[i] = tile[sc + i][d];
    unsigned short* dst = Vtb + ((size_t)bh * HDIM + d) * S_LEN + st * 64 + sc;
    *(uint4*)(dst)     = o.v[0];
    *(uint4*)(dst + 8) = o.v[1];
}

// ---------------- GEMM: C[M][N] = A[M][K=1024] * Bt[N][K]^T ----------------
// 128x128 tile, BK=32, 256 threads, global_load_lds (width 16) staging with
// XOR chunk swizzle -> 2-way conflicts only (free) on ds_read_b128 frag reads.
// R10: single-barrier DOUBLE-BUFFERED K-loop (same scheme that worked for attn
// in R9): prologue loads buf0; per iteration ONE barrier (drains last tile's
// g2l + all waves done reading the other buf), then prefetch k0+32 into the
// other buffer, then compute this tile. Load latency hides behind a full
// iteration instead of being drained immediately (R5-R9: issue->drain).
// History: R4 epilogue edit -> acc scratch spill (WRITE 2.9 GB); R8 BK=64 ->
// occupancy loss (26->17%). Epilogue text kept identical except V line
// (now [s][d] row layout, same expression shape as K). Watch WRITE_SIZE.
#define GBUF 4096   // elems per A (or B) buffer: 128*32

__global__ __launch_bounds__(256) void gemm_kernel(
    const unsigned short* __restrict__ A,
    const unsigned short* __restrict__ Bt,
    int mode,                                // 0 = QKV scatter, 1 = out + bias
    unsigned short* __restrict__ Qb,
    unsigned short* __restrict__ Kb,
    unsigned short* __restrict__ Vb,
    float* __restrict__ Out,
    const float* __restrict__ bias) {
    __shared__ unsigned short As[2 * GBUF];
    __shared__ unsigned short Bs[2 * GBUF];
    int t = threadIdx.x;
    int m0 = blockIdx.y * 128;
    int n0 = blockIdx.x * 128;
    int wave = t >> 6, lane = t & 63;
    int quad = lane >> 4, lrow = lane & 15;
    int wm = (wave & 1) * 64, wn = (wave >> 1) * 64;

    ffrag acc[4][4];
    const ffrag fz = {0.f, 0.f, 0.f, 0.f};
    for (int i = 0; i < 4; i++)
        for (int j = 0; j < 4; j++) acc[i][j] = fz;

    // staging: thread t covers chunk c0 = t and c1 = 256+t  (4 chunks/row of 32)
    int c0 = t, c1 = 256 + t;
    int r0 = c0 >> 2, cg0 = (c0 & 3) ^ ((r0 >> 1) & 3);
    int r1 = c1 >> 2, cg1 = (c1 & 3) ^ ((r1 >> 1) & 3);
    const unsigned short* A0 = A + (size_t)(m0 + r0) * D_MODEL + cg0 * 8;
    const unsigned short* A1 = A + (size_t)(m0 + r1) * D_MODEL + cg1 * 8;
    const unsigned short* B0 = Bt + (size_t)(n0 + r0) * D_MODEL + cg0 * 8;
    const unsigned short* B1 = Bt + (size_t)(n0 + r1) * D_MODEL + cg1 * 8;
    unsigned short* lA0 = &As[(wave * 64) * 8];
    unsigned short* lA1 = &As[(256 + wave * 64) * 8];
    unsigned short* lB0 = &Bs[(wave * 64) * 8];
    unsigned short* lB1 = &Bs[(256 + wave * 64) * 8];

    // prologue: preload tile 0 into buf 0
    g2l16(A0, lA0);
    g2l16(A1, lA1);
    g2l16(B0, lB0);
    g2l16(B1, lB1);

    for (int k0 = 0; k0 < D_MODEL; k0 += 32) {
        int buf = ((k0 >> 5) & 1) * GBUF;
        // ONE barrier: drains the g2l of this tile (vmcnt(0) before s_barrier)
        // and guarantees all waves finished reading the other buffer.
        __syncthreads();
        if (k0 + 32 < D_MODEL) {
            int nb = (((k0 >> 5) + 1) & 1) * GBUF;
            g2l16(A0 + k0 + 32, lA0 + nb);
            g2l16(A1 + k0 + 32, lA1 + nb);
            g2l16(B0 + k0 + 32, lB0 + nb);
            g2l16(B1 + k0 + 32, lB1 + nb);
        }
        bfrag af[4], bf[4];
        for (int mi = 0; mi < 4; mi++) {
            int row = wm + mi * 16 + lrow;
            af[mi] = ld_frag(&As[buf + row * 32 + ((quad ^ ((row >> 1) & 3)) * 8)]);
        }
        for (int ni = 0; ni < 4; ni++) {
            int row = wn + ni * 16 + lrow;
            bf[ni] = ld_frag(&Bs[buf + row * 32 + ((quad ^ ((row >> 1) & 3)) * 8)]);
        }
        for (int mi = 0; mi < 4; mi++)
            for (int ni = 0; ni < 4; ni++)
                acc[mi][ni] = __builtin_amdgcn_mfma_f32_16x16x32_bf16(af[mi], bf[ni], acc[mi][ni], 0, 0, 0);
    }

    // epilogue — C element: row = m0+wm+mi*16+quad*4+r, col = n0+wn+ni*16+lrow
    for (int mi = 0; mi < 4; mi++) {
        int row = m0 + wm + mi * 16 + quad * 4;
        for (int ni = 0; ni < 4; ni++) {
            int col = n0 + wn + ni * 16 + lrow;
            for (int r = 0; r < 4; r++) {
                float v = acc[mi][ni][r];
                int m = row + r;
                if (mode == 0) {
                    int matid = col >> 10;
                    int nn = col & 1023;
                    int h = nn >> 6, d = nn & 63;
                    int b = m >> 11, s = m & 2047;
                    size_t bh = (size_t)(b * NH + h);
                    if (matid == 0)      Qb[(bh * S_LEN + s) * HDIM + d] = f2bf(v);
                    else if (matid == 1) Kb[(bh * S_LEN + s) * HDIM + d] = f2bf(v);
                    else                 Vb[(bh * S_LEN + s) * HDIM + d] = f2bf(v);
                } else {
                    Out[(size_t)m * D_MODEL + col] = v + bias[col];
                }
            }
        }
    }
}

// ---------------- flash attention v8 (transposed-S, dbuf), causal ----------------
// grid (8, 64), 256 thr. Block bx processes q-block (15-bx) then bx -> every
// block does exactly 34 k-tile iterations (R6 lesson: uniform block length).
// DOUBLE-BUFFERED K/V staging (R9): one barrier/tile, prefetch kt+1 into the
// other buffer, compute kt. XOR-swizzled LDS; frag reads 2-way.
// S^T = K Q^T -> C layout row=key=quad*4+r, col=q=lrow.
// O^T = V^T P^T (A=V [d][key], B=P [q][key]) -> row=d, col=q.
// FIXED-SHIFT softmax: p = exp2(fma(s, SCALE2, -CSHIFT)) — exact, no overflow,
// masked -3e38 -> p=0 (R7 win). All register arrays compile-time indexed
// (R2 lesson: else scratch spill).
#define SCALE2 0.18033688f  // 1/sqrt(64) * log2(e)
#define CSHIFT 4.0f
#define KVBUF 4096          // elems per K (or V) buffer: 64*64

__global__ __launch_bounds__(256, 4) void attn_kernel(
    const unsigned short* __restrict__ Qb,
    const unsigned short* __restrict__ Kb,
    const unsigned short* __restrict__ Vtb,
    unsigned short* __restrict__ ctxb) {
    __shared__ unsigned short Ks[2 * KVBUF];      // [buf][key][d]  swizzled
    __shared__ unsigned short Vs[2 * KVBUF];      // [buf][d][key]  swizzled
    __shared__ unsigned short Ps[4 * 32 * 64];    // per wave: [q(32)][key(64)] swizzled
    int bx = blockIdx.x;   // 0..7
    int bh = blockIdx.y;   // 0..63
    int t = threadIdx.x;
    int wave = t >> 6, lane = t & 63;
    int quad = lane >> 4, lrow = lane & 15;
    int swz = lrow & 7;
    int ca = (quad ^ swz) * 8;        // physical elem offset of logical chunk quad
    int cb = ca ^ 32;                 // logical chunk quad+4

    const unsigned short* Qg = Qb + (size_t)bh * S_LEN * HDIM;
    const unsigned short* Kg = Kb + (size_t)bh * S_LEN * HDIM;
    const unsigned short* Vg = Vtb + (size_t)bh * HDIM * S_LEN;
    int b = bh >> 4, h = bh & 15;

    // staging chunk assignment (512 chunks per 64x64 tile, 2 per thread)
    int c0 = t, c1 = 256 + t;
    int kr0 = c0 >> 3, kp0 = (c0 & 7) ^ (kr0 & 7);
    int kr1 = c1 >> 3, kp1 = (c1 & 7) ^ (kr1 & 7);
    const unsigned short* pK0 = Kg + (size_t)kr0 * HDIM + kp0 * 8;
    const unsigned short* pK1 = Kg + (size_t)kr1 * HDIM + kp1 * 8;
    const unsigned short* pV0 = Vg + (size_t)kr0 * S_LEN + kp0 * 8;
    const unsigned short* pV1 = Vg + (size_t)kr1 * S_LEN + kp1 * 8;
    unsigned short* lK0 = &Ks[(wave * 64) * 8];
    unsigned short* lK1 = &Ks[(256 + wave * 64) * 8];
    unsigned short* lV0 = &Vs[(wave * 64) * 8];
    unsigned short* lV1 = &Vs[(256 + wave * 64) * 8];
    unsigned short* Pw = &Ps[wave * 32 * 64];

    for (int ph = 0; ph < 2; ph++) {
        int qbi = ph == 0 ? (15 - bx) : bx;
        int qw = qbi * 128 + wave * 32;
        int qw_u = __builtin_amdgcn_readfirstlane(qw);
        int nk = 2 * qbi + 2;

        bfrag qf[2][2];
#pragma unroll
        for (int g = 0; g < 2; g++)
#pragma unroll
            for (int c = 0; c < 2; c++)
                qf[g][c] = ld_frag(Qg + (size_t)(qw + g * 16 + lrow) * HDIM + c * 32 + quad * 8);

        ffrag acc[2][4];
        const ffrag fz = {0.f, 0.f, 0.f, 0.f};
#pragma unroll
        for (int g = 0; g < 2; g++)
#pragma unroll
            for (int d = 0; d < 4; d++) acc[g][d] = fz;
        float l_i[2] = {0.f, 0.f};

        // phase prologue: buffers free (prev phase/kernel-start), preload tile 0
        __syncthreads();
        g2l16(pK0, lK0);
        g2l16(pK1, lK1);
        g2l16(pV0, lV0);
        g2l16(pV1, lV1);

        for (int kt = 0; kt < nk; kt++) {
            int kbase = kt * 64;
            int buf = (kt & 1) * KVBUF;
            // ONE barrier: (a) drains this wave's g2l of tile kt (vmcnt(0)
            // before s_barrier), (b) all waves done reading buf[(kt+1)&1]
            // (last used by tile kt-1).
            __syncthreads();
            if (kt + 1 < nk) {
                int nb = ((kt + 1) & 1) * KVBUF;
                size_t krow_off = (size_t)(kbase + 64) * HDIM;
                g2l16(pK0 + krow_off, lK0 + nb);
                g2l16(pK1 + krow_off, lK1 + nb);
                g2l16(pV0 + kbase + 64, lV0 + nb);
                g2l16(pV1 + kbase + 64, lV1 + nb);
            }

            if (kbase > qw_u + 31) continue;   // wave-uniform compute skip

            // ---- per 16-q group: S^T = K Q^T, fixed-shift softmax, P store ----
#pragma unroll
            for (int g = 0; g < 2; g++) {
                if (kbase > qw_u + g * 16 + 15) continue;   // uniform, g static
                ffrag sf[4];
#pragma unroll
                for (int ki = 0; ki < 4; ki++) {
                    int krow = buf + (ki * 16 + lrow) * 64;
                    bfrag ka = ld_frag(&Ks[krow + ca]);
                    bfrag kb = ld_frag(&Ks[krow + cb]);
                    ffrag s = fz;
                    s = __builtin_amdgcn_mfma_f32_16x16x32_bf16(ka, qf[g][0], s, 0, 0, 0);
                    s = __builtin_amdgcn_mfma_f32_16x16x32_bf16(kb, qf[g][1], s, 0, 0, 0);
                    sf[ki] = s;
                }

                int qg = qw + g * 16 + lrow;                     // this lane's q
                bool need_mask = (kbase + 63) > (qw_u + g * 16); // uniform
                float sv[16];
                float rsum = 0.f;
#pragma unroll
                for (int ki = 0; ki < 4; ki++)
#pragma unroll
                    for (int r = 0; r < 4; r++) {
                        float v = sf[ki][r];
                        if (need_mask) {
                            int key = kbase + ki * 16 + quad * 4 + r;
                            v = (key <= qg) ? v : -3.0e38f;
                        }
                        float p = fast_exp2(__builtin_fmaf(v, SCALE2, -CSHIFT));
                        sv[ki * 4 + r] = p;
                        rsum += p;
                    }
                rsum += __shfl_xor(rsum, 16);
                rsum += __shfl_xor(rsum, 32);
                l_i[g] += rsum;
                // P store [q][key] swizzled: logical chunk 2ki+(quad>>1)
                int prow = (g * 16 + lrow) * 64;
#pragma unroll
                for (int ki = 0; ki < 4; ki++) {
                    uint2 w2;
                    w2.x = pack_bf16(sv[ki * 4 + 0], sv[ki * 4 + 1]);
                    w2.y = pack_bf16(sv[ki * 4 + 2], sv[ki * 4 + 3]);
                    int pc = ((ki * 2 + (quad >> 1)) ^ swz) * 8 + (quad & 1) * 4;
                    *(uint2*)&Pw[prow + pc] = w2;
                }
            }

            // ---- O^T += V^T P^T ----  (Pw wave-private, DS in-order: no barrier)
            bfrag pf[2][2];
#pragma unroll
            for (int g = 0; g < 2; g++) {
                if (kbase > qw_u + g * 16 + 15) continue;
                int prow = (g * 16 + lrow) * 64;
                pf[g][0] = ld_frag(&Pw[prow + ca]);
                pf[g][1] = ld_frag(&Pw[prow + cb]);
            }
#pragma unroll
            for (int di = 0; di < 4; di++) {
                int vrow = buf + (di * 16 + lrow) * 64;
                bfrag va = ld_frag(&Vs[vrow + ca]);
                bfrag vb = ld_frag(&Vs[vrow + cb]);
#pragma unroll
                for (int g = 0; g < 2; g++) {
                    if (kbase > qw_u + g * 16 + 15) continue;
                    acc[g][di] = __builtin_amdgcn_mfma_f32_16x16x32_bf16(va, pf[g][0], acc[g][di], 0, 0, 0);
                    acc[g][di] = __builtin_amdgcn_mfma_f32_16x16x32_bf16(vb, pf[g][1], acc[g][di], 0, 0, 0);
                }
            }
        }

        // epilogue: transpose O^T -> O via wave-private LDS, coalesced 16B stores
#pragma unroll
        for (int g = 0; g < 2; g++) {
            float rl = __builtin_amdgcn_rcpf(l_i[g]);
#pragma unroll
            for (int di = 0; di < 4; di++) {
                uint2 w2;
                w2.x = pack_bf16(acc[g][di][0] * rl, acc[g][di][1] * rl);
                w2.y = pack_bf16(acc[g][di][2] * rl, acc[g][di][3] * rl);
                *(uint2*)&Pw[lrow * 72 + di * 16 + quad * 4] = w2;
            }
            int ql = lane >> 3, cc = lane & 7;
#pragma unroll
            for (int p = 0; p < 2; p++) {
                uint4 vv = *(uint4*)&Pw[(p * 8 + ql) * 72 + cc * 8];
                int q = qw + g * 16 + p * 8 + ql;
                *(uint4*)(ctxb + ((size_t)b * S_LEN + q) * D_MODEL + h * HDIM + cc * 8) = vv;
            }
        }
    }
}

extern "C" void kernel_launch(void* const* d_in, const int* in_sizes, int n_in,
                              void* d_out, int out_size, void* d_ws, size_t ws_size,
                              hipStream_t stream) {
    const float* x   = (const float*)d_in[0];
    const float* W_q = (const float*)d_in[1];
    const float* W_k = (const float*)d_in[2];
    const float* W_v = (const float*)d_in[3];
    const float* W_o = (const float*)d_in[4];
    const float* b_o = (const float*)d_in[5];
    float* out = (float*)d_out;

    // workspace carve (elems, ushort).  Vb (row-layout V) aliases ctxb:
    // Vb is dead after transpose_v, before attn writes ctxb.
    unsigned short* xb   = (unsigned short*)d_ws;                    // 8192*1024
    unsigned short* Wt   = xb + (size_t)8192 * 1024;                 // 4*1024*1024
    unsigned short* Qb   = Wt + (size_t)4 * 1024 * 1024;             // 64*2048*64
    unsigned short* Kb   = Qb + (size_t)64 * 2048 * 64;
    unsigned short* Vtb  = Kb + (size_t)64 * 2048 * 64;
    unsigned short* ctxb = Vtb + (size_t)64 * 2048 * 64;             // 8192*1024
    unsigned short* Vb   = ctxb;
    unsigned short* Wto  = Wt + (size_t)3 * 1024 * 1024;

    int n8 = (BATCH * S_LEN * D_MODEL) / 8;  // 1048576
    cast_x_kernel<<<n8 / 256, 256, 0, stream>>>(x, xb, n8);
    transpose_w_kernel<<<dim3(32, 32, 4), dim3(32, 8), 0, stream>>>(W_q, W_k, W_v, W_o, Wt);
    // QKV: M=8192, N=3072 (V written row-layout [s][d])
    gemm_kernel<<<dim3(24, 64), 256, 0, stream>>>(xb, Wt, 0, Qb, Kb, Vb, nullptr, nullptr);
    // V transpose [s][d] -> [d][s]
    transpose_v_kernel<<<dim3(32, 64), 256, 0, stream>>>(Vb, Vtb);
    // attention (balanced: block bx does q-blocks 15-bx then bx)
    attn_kernel<<<dim3(8, 64), 256, 0, stream>>>(Qb, Kb, Vtb, ctxb);
    // out proj: M=8192, N=1024, + bias
    gemm_kernel<<<dim3(8, 64), 256, 0, stream>>>(ctxb, Wto, 1, nullptr, nullptr, nullptr, out, b_o);
}

// Round 11
// 294.802 us; speedup vs baseline: 1.0142x; 1.0142x over previous
//
#include <hip/hip_runtime.h>
#include <cstdint>

#define S_LEN 2048
#define D_MODEL 1024
#define NH 16
#define HDIM 64
#define BATCH 4

typedef __attribute__((ext_vector_type(8))) __bf16 bfrag;   // 8 bf16 = 4 VGPR
typedef __attribute__((ext_vector_type(4))) float ffrag;    // 4 f32 acc

__device__ __forceinline__ unsigned short f2bf(float f) {
    union { float f; uint32_t u; } v; v.f = f;
    uint32_t u = v.u;
    u += 0x7fff + ((u >> 16) & 1);   // round-to-nearest-even
    return (unsigned short)(u >> 16);
}

__device__ __forceinline__ bfrag ld_frag(const unsigned short* p) {
    union { uint4 u; bfrag b; } x;
    x.u = *(const uint4*)p;
    return x.b;
}

__device__ __forceinline__ float fast_exp2(float x) {
#if __has_builtin(__builtin_amdgcn_exp2f)
    return __builtin_amdgcn_exp2f(x);
#else
    return __expf(x * 0.6931471805599453f);
#endif
}

// pack two f32 -> packed bf16x2 (round-half-up), 3 VALU inst
__device__ __forceinline__ uint32_t pack_bf16(float a, float b) {
    union { float f; uint32_t u; } x, y; x.f = a; y.f = b;
    return __builtin_amdgcn_perm(y.u + 0x8000u, x.u + 0x8000u, 0x07060302u);
}

__device__ __forceinline__ void g2l16(const unsigned short* g, unsigned short* l) {
    __builtin_amdgcn_global_load_lds(
        (const __attribute__((address_space(1))) void*)g,
        (__attribute__((address_space(3))) void*)l, 16, 0, 0);
}

// -------- fused prep: cast x (fp32->bf16) + cast/transpose weights ----------
// blocks [0,4096): x cast, 8 elems/thread. blocks [4096,8192): W transpose,
// one 32x32 tile each (mat = (bid-4096)>>10). Block-uniform branch only.
__global__ __launch_bounds__(256) void prep_kernel(const float* __restrict__ x,
                                                   const float* __restrict__ w0,
                                                   const float* __restrict__ w1,
                                                   const float* __restrict__ w2,
                                                   const float* __restrict__ w3,
                                                   unsigned short* __restrict__ xb,
                                                   unsigned short* __restrict__ wt) {
    __shared__ float tile[32][33];
    int bid = blockIdx.x;
    int t = threadIdx.x;
    if (bid < 4096) {
        int i = bid * 256 + t;
        const float4* p = (const float4*)x + (size_t)i * 2;
        float4 a = p[0], b = p[1];
        union { unsigned short u[8]; uint4 v; } o;
        o.u[0]=f2bf(a.x); o.u[1]=f2bf(a.y); o.u[2]=f2bf(a.z); o.u[3]=f2bf(a.w);
        o.u[4]=f2bf(b.x); o.u[5]=f2bf(b.y); o.u[6]=f2bf(b.z); o.u[7]=f2bf(b.w);
        ((uint4*)xb)[i] = o.v;
    } else {
        int r = bid - 4096;
        int mat = r >> 10;
        int rem = r & 1023;
        const float* w = (mat == 0) ? w0 : (mat == 1) ? w1 : (mat == 2) ? w2 : w3;
        int n0 = (rem & 31) * 32, k0 = (rem >> 5) * 32;
        int tx = t & 31, ty = t >> 5;   // 32 x 8
        for (int i = 0; i < 32; i += 8)
            tile[ty + i][tx] = w[(size_t)(k0 + ty + i) * D_MODEL + n0 + tx];
        __syncthreads();
        unsigned short* o = wt + (size_t)mat * D_MODEL * D_MODEL;
        for (int i = 0; i < 32; i += 8)
            o[(size_t)(n0 + ty + i) * D_MODEL + (k0 + tx)] = f2bf(tile[tx][ty + i]);
    }
}

// ------------- V transpose: Vb[bh][s][d] -> Vtb[bh][d][s] (bf16) -------------
// (verified correct in round 4)
__global__ __launch_bounds__(256) void transpose_v_kernel(const unsigned short* __restrict__ Vb,
                                                          unsigned short* __restrict__ Vtb) {
    __shared__ unsigned short tile[64][72];
    int st = blockIdx.x;   // s-tile of 64
    int bh = blockIdx.y;
    int t = threadIdx.x;
    int sl = t >> 2, dc = (t & 3) * 16;
    const unsigned short* src = Vb + ((size_t)bh * S_LEN + st * 64 + sl) * HDIM + dc;
    *(uint4*)&tile[sl][dc]     = *(const uint4*)(src);
    *(uint4*)&tile[sl][dc + 8] = *(const uint4*)(src + 8);
    __syncthreads();
    int d = t >> 2, sc = (t & 3) * 16;
    union { unsigned short u[16]; uint4 v[2]; } o;
#pragma unroll
    for (int i = 0; i < 16; i++) o.u[i] = tile[sc + i][d];
    unsigned short* dst = Vtb + ((size_t)bh * HDIM + d) * S_LEN + st * 64 + sc;
    *(uint4*)(dst)     = o.v[0];
    *(uint4*)(dst + 8) = o.v[1];
}

// ---------------- GEMM: C[M][N] = A[M][K=1024] * Bt[N][K]^T ----------------
// 128x128 tile, BK=32, 256 threads, global_load_lds (width 16) staging with
// XOR chunk swizzle -> 2-way conflicts only (free) on ds_read_b128 frag reads.
// R10: single-barrier DOUBLE-BUFFERED K-loop: prologue loads buf0; per
// iteration ONE barrier, then prefetch k0+32 into the other buffer, then
// compute this tile. Load latency hides behind a full iteration.
// History: R4 epilogue edit -> acc scratch spill (WRITE 2.9 GB); R8 BK=64 ->
// occupancy loss (26->17%). Keep text stable; watch WRITE_SIZE.
#define GBUF 4096   // elems per A (or B) buffer: 128*32

__global__ __launch_bounds__(256) void gemm_kernel(
    const unsigned short* __restrict__ A,
    const unsigned short* __restrict__ Bt,
    int mode,                                // 0 = QKV scatter, 1 = out + bias
    unsigned short* __restrict__ Qb,
    unsigned short* __restrict__ Kb,
    unsigned short* __restrict__ Vb,
    float* __restrict__ Out,
    const float* __restrict__ bias) {
    __shared__ unsigned short As[2 * GBUF];
    __shared__ unsigned short Bs[2 * GBUF];
    int t = threadIdx.x;
    int m0 = blockIdx.y * 128;
    int n0 = blockIdx.x * 128;
    int wave = t >> 6, lane = t & 63;
    int quad = lane >> 4, lrow = lane & 15;
    int wm = (wave & 1) * 64, wn = (wave >> 1) * 64;

    ffrag acc[4][4];
    const ffrag fz = {0.f, 0.f, 0.f, 0.f};
    for (int i = 0; i < 4; i++)
        for (int j = 0; j < 4; j++) acc[i][j] = fz;

    // staging: thread t covers chunk c0 = t and c1 = 256+t  (4 chunks/row of 32)
    int c0 = t, c1 = 256 + t;
    int r0 = c0 >> 2, cg0 = (c0 & 3) ^ ((r0 >> 1) & 3);
    int r1 = c1 >> 2, cg1 = (c1 & 3) ^ ((r1 >> 1) & 3);
    const unsigned short* A0 = A + (size_t)(m0 + r0) * D_MODEL + cg0 * 8;
    const unsigned short* A1 = A + (size_t)(m0 + r1) * D_MODEL + cg1 * 8;
    const unsigned short* B0 = Bt + (size_t)(n0 + r0) * D_MODEL + cg0 * 8;
    const unsigned short* B1 = Bt + (size_t)(n0 + r1) * D_MODEL + cg1 * 8;
    unsigned short* lA0 = &As[(wave * 64) * 8];
    unsigned short* lA1 = &As[(256 + wave * 64) * 8];
    unsigned short* lB0 = &Bs[(wave * 64) * 8];
    unsigned short* lB1 = &Bs[(256 + wave * 64) * 8];

    // prologue: preload tile 0 into buf 0
    g2l16(A0, lA0);
    g2l16(A1, lA1);
    g2l16(B0, lB0);
    g2l16(B1, lB1);

    for (int k0 = 0; k0 < D_MODEL; k0 += 32) {
        int buf = ((k0 >> 5) & 1) * GBUF;
        // ONE barrier: drains the g2l of this tile (vmcnt(0) before s_barrier)
        // and guarantees all waves finished reading the other buffer.
        __syncthreads();
        if (k0 + 32 < D_MODEL) {
            int nb = (((k0 >> 5) + 1) & 1) * GBUF;
            g2l16(A0 + k0 + 32, lA0 + nb);
            g2l16(A1 + k0 + 32, lA1 + nb);
            g2l16(B0 + k0 + 32, lB0 + nb);
            g2l16(B1 + k0 + 32, lB1 + nb);
        }
        bfrag af[4], bf[4];
        for (int mi = 0; mi < 4; mi++) {
            int row = wm + mi * 16 + lrow;
            af[mi] = ld_frag(&As[buf + row * 32 + ((quad ^ ((row >> 1) & 3)) * 8)]);
        }
        for (int ni = 0; ni < 4; ni++) {
            int row = wn + ni * 16 + lrow;
            bf[ni] = ld_frag(&Bs[buf + row * 32 + ((quad ^ ((row >> 1) & 3)) * 8)]);
        }
        for (int mi = 0; mi < 4; mi++)
            for (int ni = 0; ni < 4; ni++)
                acc[mi][ni] = __builtin_amdgcn_mfma_f32_16x16x32_bf16(af[mi], bf[ni], acc[mi][ni], 0, 0, 0);
    }

    // epilogue — C element: row = m0+wm+mi*16+quad*4+r, col = n0+wn+ni*16+lrow
    for (int mi = 0; mi < 4; mi++) {
        int row = m0 + wm + mi * 16 + quad * 4;
        for (int ni = 0; ni < 4; ni++) {
            int col = n0 + wn + ni * 16 + lrow;
            for (int r = 0; r < 4; r++) {
                float v = acc[mi][ni][r];
                int m = row + r;
                if (mode == 0) {
                    int matid = col >> 10;
                    int nn = col & 1023;
                    int h = nn >> 6, d = nn & 63;
                    int b = m >> 11, s = m & 2047;
                    size_t bh = (size_t)(b * NH + h);
                    if (matid == 0)      Qb[(bh * S_LEN + s) * HDIM + d] = f2bf(v);
                    else if (matid == 1) Kb[(bh * S_LEN + s) * HDIM + d] = f2bf(v);
                    else                 Vb[(bh * S_LEN + s) * HDIM + d] = f2bf(v);
                } else {
                    Out[(size_t)m * D_MODEL + col] = v + bias[col];
                }
            }
        }
    }
}

// ---------------- flash attention v9 (transposed-S, dbuf), causal ----------------
// grid (8, 64), 256 thr. Block bx processes q-block (15-bx) then bx -> every
// block does exactly 34 k-tile iterations (R6 lesson: uniform block length).
// DOUBLE-BUFFERED K/V staging (R9): one barrier/tile, prefetch kt+1 into the
// other buffer, compute kt. XOR-swizzled LDS; frag reads 2-way.
// S^T = K Q^T -> C layout row=key=quad*4+r, col=q=lrow.
// O^T = V^T P^T (A=V [d][key], B=P [q][key]) -> row=d, col=q.
// FIXED-SHIFT softmax: p = exp2(fma(s, SCALE2, -CSHIFT)) — exact, no overflow,
// masked -3e38 -> p=0 (R7 win).
// R11: l computed via ONES-MFMA: acc_l = mfma(ones, P-frag) -> D[m][q] =
// sum_k P[q][k], all rows identical, lane lrow=q holds l(q) — removes the
// 16-add rsum chain + 2 shfl_xor per group from the busy VALU pipe and puts
// 4 extra MFMAs on the idle matrix pipe. l now derives from bf16-rounded P,
// consistent with the PV numerator.
// All register arrays compile-time indexed (R2 lesson: else scratch spill).
#define SCALE2 0.18033688f  // 1/sqrt(64) * log2(e)
#define CSHIFT 4.0f
#define KVBUF 4096          // elems per K (or V) buffer: 64*64

__global__ __launch_bounds__(256, 4) void attn_kernel(
    const unsigned short* __restrict__ Qb,
    const unsigned short* __restrict__ Kb,
    const unsigned short* __restrict__ Vtb,
    unsigned short* __restrict__ ctxb) {
    __shared__ unsigned short Ks[2 * KVBUF];      // [buf][key][d]  swizzled
    __shared__ unsigned short Vs[2 * KVBUF];      // [buf][d][key]  swizzled
    __shared__ unsigned short Ps[4 * 32 * 64];    // per wave: [q(32)][key(64)] swizzled
    int bx = blockIdx.x;   // 0..7
    int bh = blockIdx.y;   // 0..63
    int t = threadIdx.x;
    int wave = t >> 6, lane = t & 63;
    int quad = lane >> 4, lrow = lane & 15;
    int swz = lrow & 7;
    int ca = (quad ^ swz) * 8;        // physical elem offset of logical chunk quad
    int cb = ca ^ 32;                 // logical chunk quad+4

    union { uint4 u; bfrag b; } one_u;
    one_u.u.x = 0x3F803F80u; one_u.u.y = 0x3F803F80u;
    one_u.u.z = 0x3F803F80u; one_u.u.w = 0x3F803F80u;
    bfrag onef = one_u.b;             // all-ones A-frag for l row-sum MFMA

    const unsigned short* Qg = Qb + (size_t)bh * S_LEN * HDIM;
    const unsigned short* Kg = Kb + (size_t)bh * S_LEN * HDIM;
    const unsigned short* Vg = Vtb + (size_t)bh * HDIM * S_LEN;
    int b = bh >> 4, h = bh & 15;

    // staging chunk assignment (512 chunks per 64x64 tile, 2 per thread)
    int c0 = t, c1 = 256 + t;
    int kr0 = c0 >> 3, kp0 = (c0 & 7) ^ (kr0 & 7);
    int kr1 = c1 >> 3, kp1 = (c1 & 7) ^ (kr1 & 7);
    const unsigned short* pK0 = Kg + (size_t)kr0 * HDIM + kp0 * 8;
    const unsigned short* pK1 = Kg + (size_t)kr1 * HDIM + kp1 * 8;
    const unsigned short* pV0 = Vg + (size_t)kr0 * S_LEN + kp0 * 8;
    const unsigned short* pV1 = Vg + (size_t)kr1 * S_LEN + kp1 * 8;
    unsigned short* lK0 = &Ks[(wave * 64) * 8];
    unsigned short* lK1 = &Ks[(256 + wave * 64) * 8];
    unsigned short* lV0 = &Vs[(wave * 64) * 8];
    unsigned short* lV1 = &Vs[(256 + wave * 64) * 8];
    unsigned short* Pw = &Ps[wave * 32 * 64];

    for (int ph = 0; ph < 2; ph++) {
        int qbi = ph == 0 ? (15 - bx) : bx;
        int qw = qbi * 128 + wave * 32;
        int qw_u = __builtin_amdgcn_readfirstlane(qw);
        int nk = 2 * qbi + 2;

        bfrag qf[2][2];
#pragma unroll
        for (int g = 0; g < 2; g++)
#pragma unroll
            for (int c = 0; c < 2; c++)
                qf[g][c] = ld_frag(Qg + (size_t)(qw + g * 16 + lrow) * HDIM + c * 32 + quad * 8);

        ffrag acc[2][4];
        ffrag acc_l[2];
        const ffrag fz = {0.f, 0.f, 0.f, 0.f};
#pragma unroll
        for (int g = 0; g < 2; g++) {
#pragma unroll
            for (int d = 0; d < 4; d++) acc[g][d] = fz;
            acc_l[g] = fz;
        }

        // phase prologue: buffers free (prev phase/kernel-start), preload tile 0
        __syncthreads();
        g2l16(pK0, lK0);
        g2l16(pK1, lK1);
        g2l16(pV0, lV0);
        g2l16(pV1, lV1);

        for (int kt = 0; kt < nk; kt++) {
            int kbase = kt * 64;
            int buf = (kt & 1) * KVBUF;
            // ONE barrier: (a) drains this wave's g2l of tile kt (vmcnt(0)
            // before s_barrier), (b) all waves done reading buf[(kt+1)&1]
            // (last used by tile kt-1).
            __syncthreads();
            if (kt + 1 < nk) {
                int nb = ((kt + 1) & 1) * KVBUF;
                size_t krow_off = (size_t)(kbase + 64) * HDIM;
                g2l16(pK0 + krow_off, lK0 + nb);
                g2l16(pK1 + krow_off, lK1 + nb);
                g2l16(pV0 + kbase + 64, lV0 + nb);
                g2l16(pV1 + kbase + 64, lV1 + nb);
            }

            if (kbase > qw_u + 31) continue;   // wave-uniform compute skip

            // ---- per 16-q group: S^T = K Q^T, fixed-shift softmax, P store ----
#pragma unroll
            for (int g = 0; g < 2; g++) {
                if (kbase > qw_u + g * 16 + 15) continue;   // uniform, g static
                ffrag sf[4];
#pragma unroll
                for (int ki = 0; ki < 4; ki++) {
                    int krow = buf + (ki * 16 + lrow) * 64;
                    bfrag ka = ld_frag(&Ks[krow + ca]);
                    bfrag kb = ld_frag(&Ks[krow + cb]);
                    ffrag s = fz;
                    s = __builtin_amdgcn_mfma_f32_16x16x32_bf16(ka, qf[g][0], s, 0, 0, 0);
                    s = __builtin_amdgcn_mfma_f32_16x16x32_bf16(kb, qf[g][1], s, 0, 0, 0);
                    sf[ki] = s;
                }

                int qg = qw + g * 16 + lrow;                     // this lane's q
                bool need_mask = (kbase + 63) > (qw_u + g * 16); // uniform
                float sv[16];
#pragma unroll
                for (int ki = 0; ki < 4; ki++)
#pragma unroll
                    for (int r = 0; r < 4; r++) {
                        float v = sf[ki][r];
                        if (need_mask) {
                            int key = kbase + ki * 16 + quad * 4 + r;
                            v = (key <= qg) ? v : -3.0e38f;
                        }
                        sv[ki * 4 + r] = fast_exp2(__builtin_fmaf(v, SCALE2, -CSHIFT));
                    }
                // P store [q][key] swizzled: logical chunk 2ki+(quad>>1)
                int prow = (g * 16 + lrow) * 64;
#pragma unroll
                for (int ki = 0; ki < 4; ki++) {
                    uint2 w2;
                    w2.x = pack_bf16(sv[ki * 4 + 0], sv[ki * 4 + 1]);
                    w2.y = pack_bf16(sv[ki * 4 + 2], sv[ki * 4 + 3]);
                    int pc = ((ki * 2 + (quad >> 1)) ^ swz) * 8 + (quad & 1) * 4;
                    *(uint2*)&Pw[prow + pc] = w2;
                }
            }

            // ---- O^T += V^T P^T ----  (Pw wave-private, DS in-order: no barrier)
            bfrag pf[2][2];
#pragma unroll
            for (int g = 0; g < 2; g++) {
                if (kbase > qw_u + g * 16 + 15) continue;
                int prow = (g * 16 + lrow) * 64;
                pf[g][0] = ld_frag(&Pw[prow + ca]);
                pf[g][1] = ld_frag(&Pw[prow + cb]);
                // l row-sum on the idle matrix pipe (replaces rsum chain)
                acc_l[g] = __builtin_amdgcn_mfma_f32_16x16x32_bf16(onef, pf[g][0], acc_l[g], 0, 0, 0);
                acc_l[g] = __builtin_amdgcn_mfma_f32_16x16x32_bf16(onef, pf[g][1], acc_l[g], 0, 0, 0);
            }
#pragma unroll
            for (int di = 0; di < 4; di++) {
                int vrow = buf + (di * 16 + lrow) * 64;
                bfrag va = ld_frag(&Vs[vrow + ca]);
                bfrag vb = ld_frag(&Vs[vrow + cb]);
#pragma unroll
                for (int g = 0; g < 2; g++) {
                    if (kbase > qw_u + g * 16 + 15) continue;
                    acc[g][di] = __builtin_amdgcn_mfma_f32_16x16x32_bf16(va, pf[g][0], acc[g][di], 0, 0, 0);
                    acc[g][di] = __builtin_amdgcn_mfma_f32_16x16x32_bf16(vb, pf[g][1], acc[g][di], 0, 0, 0);
                }
            }
        }

        // epilogue: transpose O^T -> O via wave-private LDS, coalesced 16B stores
#pragma unroll
        for (int g = 0; g < 2; g++) {
            float rl = __builtin_amdgcn_rcpf(acc_l[g][0]);  // all rows equal; lane lrow=q
#pragma unroll
            for (int di = 0; di < 4; di++) {
                uint2 w2;
                w2.x = pack_bf16(acc[g][di][0] * rl, acc[g][di][1] * rl);
                w2.y = pack_bf16(acc[g][di][2] * rl, acc[g][di][3] * rl);
                *(uint2*)&Pw[lrow * 72 + di * 16 + quad * 4] = w2;
            }
            int ql = lane >> 3, cc = lane & 7;
#pragma unroll
            for (int p = 0; p < 2; p++) {
                uint4 vv = *(uint4*)&Pw[(p * 8 + ql) * 72 + cc * 8];
                int q = qw + g * 16 + p * 8 + ql;
                *(uint4*)(ctxb + ((size_t)b * S_LEN + q) * D_MODEL + h * HDIM + cc * 8) = vv;
            }
        }
    }
}

extern "C" void kernel_launch(void* const* d_in, const int* in_sizes, int n_in,
                              void* d_out, int out_size, void* d_ws, size_t ws_size,
                              hipStream_t stream) {
    const float* x   = (const float*)d_in[0];
    const float* W_q = (const float*)d_in[1];
    const float* W_k = (const float*)d_in[2];
    const float* W_v = (const float*)d_in[3];
    const float* W_o = (const float*)d_in[4];
    const float* b_o = (const float*)d_in[5];
    float* out = (float*)d_out;

    // workspace carve (elems, ushort).  Vb (row-layout V) aliases ctxb:
    // Vb is dead after transpose_v, before attn writes ctxb.
    unsigned short* xb   = (unsigned short*)d_ws;                    // 8192*1024
    unsigned short* Wt   = xb + (size_t)8192 * 1024;                 // 4*1024*1024
    unsigned short* Qb   = Wt + (size_t)4 * 1024 * 1024;             // 64*2048*64
    unsigned short* Kb   = Qb + (size_t)64 * 2048 * 64;
    unsigned short* Vtb  = Kb + (size_t)64 * 2048 * 64;
    unsigned short* ctxb = Vtb + (size_t)64 * 2048 * 64;             // 8192*1024
    unsigned short* Vb   = ctxb;
    unsigned short* Wto  = Wt + (size_t)3 * 1024 * 1024;

    // fused cast + weight transpose (one launch)
    prep_kernel<<<8192, 256, 0, stream>>>(x, W_q, W_k, W_v, W_o, xb, Wt);
    // QKV: M=8192, N=3072 (V written row-layout [s][d])
    gemm_kernel<<<dim3(24, 64), 256, 0, stream>>>(xb, Wt, 0, Qb, Kb, Vb, nullptr, nullptr);
    // V transpose [s][d] -> [d][s]
    transpose_v_kernel<<<dim3(32, 64), 256, 0, stream>>>(Vb, Vtb);
    // attention (balanced: block bx does q-blocks 15-bx then bx)
    attn_kernel<<<dim3(8, 64), 256, 0, stream>>>(Qb, Kb, Vtb, ctxb);
    // out proj: M=8192, N=1024, + bias
    gemm_kernel<<<dim3(8, 64), 256, 0, stream>>>(ctxb, Wto, 1, nullptr, nullptr, nullptr, out, b_o);
}

// Round 12
// 287.999 us; speedup vs baseline: 1.0382x; 1.0236x over previous
//
#include <hip/hip_runtime.h>
#include <cstdint>

#define S_LEN 2048
#define D_MODEL 1024
#define NH 16
#define HDIM 64
#define BATCH 4

typedef __attribute__((ext_vector_type(8))) __bf16 bfrag;   // 8 bf16 = 4 VGPR
typedef __attribute__((ext_vector_type(4))) float ffrag;    // 4 f32 acc

__device__ __forceinline__ unsigned short f2bf(float f) {
    union { float f; uint32_t u; } v; v.f = f;
    uint32_t u = v.u;
    u += 0x7fff + ((u >> 16) & 1);   // round-to-nearest-even
    return (unsigned short)(u >> 16);
}

__device__ __forceinline__ bfrag ld_frag(const unsigned short* p) {
    union { uint4 u; bfrag b; } x;
    x.u = *(const uint4*)p;
    return x.b;
}

__device__ __forceinline__ float fast_exp2(float x) {
#if __has_builtin(__builtin_amdgcn_exp2f)
    return __builtin_amdgcn_exp2f(x);
#else
    return __expf(x * 0.6931471805599453f);
#endif
}

// pack two f32 -> packed bf16x2 (round-half-up), 3 VALU inst
__device__ __forceinline__ uint32_t pack_bf16(float a, float b) {
    union { float f; uint32_t u; } x, y; x.f = a; y.f = b;
    return __builtin_amdgcn_perm(y.u + 0x8000u, x.u + 0x8000u, 0x07060302u);
}

__device__ __forceinline__ void g2l16(const unsigned short* g, unsigned short* l) {
    __builtin_amdgcn_global_load_lds(
        (const __attribute__((address_space(1))) void*)g,
        (__attribute__((address_space(3))) void*)l, 16, 0, 0);
}

// -------- fused prep: cast x (fp32->bf16) + cast/transpose weights ----------
// blocks [0,4096): x cast, 8 elems/thread. blocks [4096,8192): W transpose,
// one 32x32 tile each (mat = (bid-4096)>>10). Block-uniform branch only.
__global__ __launch_bounds__(256) void prep_kernel(const float* __restrict__ x,
                                                   const float* __restrict__ w0,
                                                   const float* __restrict__ w1,
                                                   const float* __restrict__ w2,
                                                   const float* __restrict__ w3,
                                                   unsigned short* __restrict__ xb,
                                                   unsigned short* __restrict__ wt) {
    __shared__ float tile[32][33];
    int bid = blockIdx.x;
    int t = threadIdx.x;
    if (bid < 4096) {
        int i = bid * 256 + t;
        const float4* p = (const float4*)x + (size_t)i * 2;
        float4 a = p[0], b = p[1];
        union { unsigned short u[8]; uint4 v; } o;
        o.u[0]=f2bf(a.x); o.u[1]=f2bf(a.y); o.u[2]=f2bf(a.z); o.u[3]=f2bf(a.w);
        o.u[4]=f2bf(b.x); o.u[5]=f2bf(b.y); o.u[6]=f2bf(b.z); o.u[7]=f2bf(b.w);
        ((uint4*)xb)[i] = o.v;
    } else {
        int r = bid - 4096;
        int mat = r >> 10;
        int rem = r & 1023;
        const float* w = (mat == 0) ? w0 : (mat == 1) ? w1 : (mat == 2) ? w2 : w3;
        int n0 = (rem & 31) * 32, k0 = (rem >> 5) * 32;
        int tx = t & 31, ty = t >> 5;   // 32 x 8
        for (int i = 0; i < 32; i += 8)
            tile[ty + i][tx] = w[(size_t)(k0 + ty + i) * D_MODEL + n0 + tx];
        __syncthreads();
        unsigned short* o = wt + (size_t)mat * D_MODEL * D_MODEL;
        for (int i = 0; i < 32; i += 8)
            o[(size_t)(n0 + ty + i) * D_MODEL + (k0 + tx)] = f2bf(tile[tx][ty + i]);
    }
}

// ------------- V transpose: Vb[bh][s][d] -> Vtb[bh][d][s] (bf16) -------------
// (verified correct in round 4)
__global__ __launch_bounds__(256) void transpose_v_kernel(const unsigned short* __restrict__ Vb,
                                                          unsigned short* __restrict__ Vtb) {
    __shared__ unsigned short tile[64][72];
    int st = blockIdx.x;   // s-tile of 64
    int bh = blockIdx.y;
    int t = threadIdx.x;
    int sl = t >> 2, dc = (t & 3) * 16;
    const unsigned short* src = Vb + ((size_t)bh * S_LEN + st * 64 + sl) * HDIM + dc;
    *(uint4*)&tile[sl][dc]     = *(const uint4*)(src);
    *(uint4*)&tile[sl][dc + 8] = *(const uint4*)(src + 8);
    __syncthreads();
    int d = t >> 2, sc = (t & 3) * 16;
    union { unsigned short u[16]; uint4 v[2]; } o;
#pragma unroll
    for (int i = 0; i < 16; i++) o.u[i] = tile[sc + i][d];
    unsigned short* dst = Vtb + ((size_t)bh * HDIM + d) * S_LEN + st * 64 + sc;
    *(uint4*)(dst)     = o.v[0];
    *(uint4*)(dst + 8) = o.v[1];
}

// ---------------- GEMM: C[M][N] = A[M][K=1024] * Bt[N][K]^T ----------------
// 128x128 tile, BK=32, 256 threads, global_load_lds (width 16) staging with
// XOR chunk swizzle -> 2-way conflicts only (free) on ds_read_b128 frag reads.
// R10: single-barrier DOUBLE-BUFFERED K-loop: prologue loads buf0; per
// iteration ONE barrier, then prefetch k0+32 into the other buffer, then
// compute this tile. Load latency hides behind a full iteration.
// History: R4 epilogue edit -> acc scratch spill (WRITE 2.9 GB); R8 BK=64 ->
// occupancy loss (26->17%). Keep text stable; watch WRITE_SIZE.
#define GBUF 4096   // elems per A (or B) buffer: 128*32

__global__ __launch_bounds__(256) void gemm_kernel(
    const unsigned short* __restrict__ A,
    const unsigned short* __restrict__ Bt,
    int mode,                                // 0 = QKV scatter, 1 = out + bias
    unsigned short* __restrict__ Qb,
    unsigned short* __restrict__ Kb,
    unsigned short* __restrict__ Vb,
    float* __restrict__ Out,
    const float* __restrict__ bias) {
    __shared__ unsigned short As[2 * GBUF];
    __shared__ unsigned short Bs[2 * GBUF];
    int t = threadIdx.x;
    int m0 = blockIdx.y * 128;
    int n0 = blockIdx.x * 128;
    int wave = t >> 6, lane = t & 63;
    int quad = lane >> 4, lrow = lane & 15;
    int wm = (wave & 1) * 64, wn = (wave >> 1) * 64;

    ffrag acc[4][4];
    const ffrag fz = {0.f, 0.f, 0.f, 0.f};
    for (int i = 0; i < 4; i++)
        for (int j = 0; j < 4; j++) acc[i][j] = fz;

    // staging: thread t covers chunk c0 = t and c1 = 256+t  (4 chunks/row of 32)
    int c0 = t, c1 = 256 + t;
    int r0 = c0 >> 2, cg0 = (c0 & 3) ^ ((r0 >> 1) & 3);
    int r1 = c1 >> 2, cg1 = (c1 & 3) ^ ((r1 >> 1) & 3);
    const unsigned short* A0 = A + (size_t)(m0 + r0) * D_MODEL + cg0 * 8;
    const unsigned short* A1 = A + (size_t)(m0 + r1) * D_MODEL + cg1 * 8;
    const unsigned short* B0 = Bt + (size_t)(n0 + r0) * D_MODEL + cg0 * 8;
    const unsigned short* B1 = Bt + (size_t)(n0 + r1) * D_MODEL + cg1 * 8;
    unsigned short* lA0 = &As[(wave * 64) * 8];
    unsigned short* lA1 = &As[(256 + wave * 64) * 8];
    unsigned short* lB0 = &Bs[(wave * 64) * 8];
    unsigned short* lB1 = &Bs[(256 + wave * 64) * 8];

    // prologue: preload tile 0 into buf 0
    g2l16(A0, lA0);
    g2l16(A1, lA1);
    g2l16(B0, lB0);
    g2l16(B1, lB1);

    for (int k0 = 0; k0 < D_MODEL; k0 += 32) {
        int buf = ((k0 >> 5) & 1) * GBUF;
        // ONE barrier: drains the g2l of this tile (vmcnt(0) before s_barrier)
        // and guarantees all waves finished reading the other buffer.
        __syncthreads();
        if (k0 + 32 < D_MODEL) {
            int nb = (((k0 >> 5) + 1) & 1) * GBUF;
            g2l16(A0 + k0 + 32, lA0 + nb);
            g2l16(A1 + k0 + 32, lA1 + nb);
            g2l16(B0 + k0 + 32, lB0 + nb);
            g2l16(B1 + k0 + 32, lB1 + nb);
        }
        bfrag af[4], bf[4];
        for (int mi = 0; mi < 4; mi++) {
            int row = wm + mi * 16 + lrow;
            af[mi] = ld_frag(&As[buf + row * 32 + ((quad ^ ((row >> 1) & 3)) * 8)]);
        }
        for (int ni = 0; ni < 4; ni++) {
            int row = wn + ni * 16 + lrow;
            bf[ni] = ld_frag(&Bs[buf + row * 32 + ((quad ^ ((row >> 1) & 3)) * 8)]);
        }
        for (int mi = 0; mi < 4; mi++)
            for (int ni = 0; ni < 4; ni++)
                acc[mi][ni] = __builtin_amdgcn_mfma_f32_16x16x32_bf16(af[mi], bf[ni], acc[mi][ni], 0, 0, 0);
    }

    // epilogue — C element: row = m0+wm+mi*16+quad*4+r, col = n0+wn+ni*16+lrow
    for (int mi = 0; mi < 4; mi++) {
        int row = m0 + wm + mi * 16 + quad * 4;
        for (int ni = 0; ni < 4; ni++) {
            int col = n0 + wn + ni * 16 + lrow;
            for (int r = 0; r < 4; r++) {
                float v = acc[mi][ni][r];
                int m = row + r;
                if (mode == 0) {
                    int matid = col >> 10;
                    int nn = col & 1023;
                    int h = nn >> 6, d = nn & 63;
                    int b = m >> 11, s = m & 2047;
                    size_t bh = (size_t)(b * NH + h);
                    if (matid == 0)      Qb[(bh * S_LEN + s) * HDIM + d] = f2bf(v);
                    else if (matid == 1) Kb[(bh * S_LEN + s) * HDIM + d] = f2bf(v);
                    else                 Vb[(bh * S_LEN + s) * HDIM + d] = f2bf(v);
                } else {
                    Out[(size_t)m * D_MODEL + col] = v + bias[col];
                }
            }
        }
    }
}

// ---------------- flash attention v10 (transposed-S, dbuf, split-q), causal ----------------
// R12: 64-row q chunks, grid (16, 64) = 1024 blocks = exactly 4/CU co-resident
// (R5-R11's 512 blocks capped residency at 2/CU -> Occupancy 19%, both pipes
// idle). Block bx processes chunk (31-bx) then bx -> exactly 33 k-tiles per
// block (R6 lesson: uniform length). Each wave owns ONE 16-q group: the g-loop
// and all wave-skip guards are gone; every wave computes every tile; only the
// diagonal tile masks (block-uniform branch). LDS 40 KB = Ks/Vs dbuf 32K +
// Ps 8K -> 4 blocks/CU.
// DOUBLE-BUFFERED K/V staging (R9): one barrier/tile, prefetch kt+1 into the
// other buffer, compute kt. XOR-swizzled LDS; frag reads 2-way.
// S^T = K Q^T -> C layout row=key=quad*4+r, col=q=lrow.
// O^T = V^T P^T (A=V [d][key], B=P [q][key]) -> row=d, col=q.
// FIXED-SHIFT softmax: p = exp2(fma(s, SCALE2, -CSHIFT)) — exact, no overflow,
// masked -3e38 -> p=0 (R7 win). l via ones-MFMA on the matrix pipe (R11 win).
// All register arrays compile-time indexed (R2 lesson: else scratch spill).
#define SCALE2 0.18033688f  // 1/sqrt(64) * log2(e)
#define CSHIFT 4.0f
#define KVBUF 4096          // elems per K (or V) buffer: 64*64

__global__ __launch_bounds__(256, 4) void attn_kernel(
    const unsigned short* __restrict__ Qb,
    const unsigned short* __restrict__ Kb,
    const unsigned short* __restrict__ Vtb,
    unsigned short* __restrict__ ctxb) {
    __shared__ unsigned short Ks[2 * KVBUF];      // [buf][key][d]  swizzled
    __shared__ unsigned short Vs[2 * KVBUF];      // [buf][d][key]  swizzled
    __shared__ unsigned short Ps[4 * 16 * 64];    // per wave: [q(16)][key(64)] swizzled
    int bx = blockIdx.x;   // 0..15
    int bh = blockIdx.y;   // 0..63
    int t = threadIdx.x;
    int wave = t >> 6, lane = t & 63;
    int quad = lane >> 4, lrow = lane & 15;
    int swz = lrow & 7;
    int ca = (quad ^ swz) * 8;        // physical elem offset of logical chunk quad
    int cb = ca ^ 32;                 // logical chunk quad+4

    union { uint4 u; bfrag b; } one_u;
    one_u.u.x = 0x3F803F80u; one_u.u.y = 0x3F803F80u;
    one_u.u.z = 0x3F803F80u; one_u.u.w = 0x3F803F80u;
    bfrag onef = one_u.b;             // all-ones A-frag for l row-sum MFMA

    const unsigned short* Qg = Qb + (size_t)bh * S_LEN * HDIM;
    const unsigned short* Kg = Kb + (size_t)bh * S_LEN * HDIM;
    const unsigned short* Vg = Vtb + (size_t)bh * HDIM * S_LEN;
    int b = bh >> 4, h = bh & 15;

    // staging chunk assignment (512 chunks per 64x64 tile, 2 per thread)
    int c0 = t, c1 = 256 + t;
    int kr0 = c0 >> 3, kp0 = (c0 & 7) ^ (kr0 & 7);
    int kr1 = c1 >> 3, kp1 = (c1 & 7) ^ (kr1 & 7);
    const unsigned short* pK0 = Kg + (size_t)kr0 * HDIM + kp0 * 8;
    const unsigned short* pK1 = Kg + (size_t)kr1 * HDIM + kp1 * 8;
    const unsigned short* pV0 = Vg + (size_t)kr0 * S_LEN + kp0 * 8;
    const unsigned short* pV1 = Vg + (size_t)kr1 * S_LEN + kp1 * 8;
    unsigned short* lK0 = &Ks[(wave * 64) * 8];
    unsigned short* lK1 = &Ks[(256 + wave * 64) * 8];
    unsigned short* lV0 = &Vs[(wave * 64) * 8];
    unsigned short* lV1 = &Vs[(256 + wave * 64) * 8];
    unsigned short* Pw = &Ps[wave * 16 * 64];

    for (int ph = 0; ph < 2; ph++) {
        int qc = ph == 0 ? (31 - bx) : bx;   // 64-row q chunk index
        int qw = qc * 64 + wave * 16;
        int nk = qc + 1;

        bfrag qf[2];
#pragma unroll
        for (int c = 0; c < 2; c++)
            qf[c] = ld_frag(Qg + (size_t)(qw + lrow) * HDIM + c * 32 + quad * 8);

        ffrag acc[4];
        ffrag acc_l;
        const ffrag fz = {0.f, 0.f, 0.f, 0.f};
#pragma unroll
        for (int d = 0; d < 4; d++) acc[d] = fz;
        acc_l = fz;

        // phase prologue: buffers free (prev phase/kernel-start), preload tile 0
        __syncthreads();
        g2l16(pK0, lK0);
        g2l16(pK1, lK1);
        g2l16(pV0, lV0);
        g2l16(pV1, lV1);

        for (int kt = 0; kt < nk; kt++) {
            int kbase = kt * 64;
            int buf = (kt & 1) * KVBUF;
            // ONE barrier: (a) drains this wave's g2l of tile kt (vmcnt(0)
            // before s_barrier), (b) all waves done reading buf[(kt+1)&1].
            __syncthreads();
            if (kt + 1 < nk) {
                int nb = ((kt + 1) & 1) * KVBUF;
                size_t krow_off = (size_t)(kbase + 64) * HDIM;
                g2l16(pK0 + krow_off, lK0 + nb);
                g2l16(pK1 + krow_off, lK1 + nb);
                g2l16(pV0 + kbase + 64, lV0 + nb);
                g2l16(pV1 + kbase + 64, lV1 + nb);
            }

            // ---- S^T = K Q^T ----
            ffrag sf[4];
#pragma unroll
            for (int ki = 0; ki < 4; ki++) {
                int krow = buf + (ki * 16 + lrow) * 64;
                bfrag ka = ld_frag(&Ks[krow + ca]);
                bfrag kb = ld_frag(&Ks[krow + cb]);
                ffrag s = fz;
                s = __builtin_amdgcn_mfma_f32_16x16x32_bf16(ka, qf[0], s, 0, 0, 0);
                s = __builtin_amdgcn_mfma_f32_16x16x32_bf16(kb, qf[1], s, 0, 0, 0);
                sf[ki] = s;
            }

            // ---- fixed-shift softmax (mask only on the diagonal tile) ----
            int qg = qw + lrow;                  // this lane's q
            bool need_mask = (kt == nk - 1);     // block-uniform
            float sv[16];
#pragma unroll
            for (int ki = 0; ki < 4; ki++)
#pragma unroll
                for (int r = 0; r < 4; r++) {
                    float v = sf[ki][r];
                    if (need_mask) {
                        int key = kbase + ki * 16 + quad * 4 + r;
                        v = (key <= qg) ? v : -3.0e38f;
                    }
                    sv[ki * 4 + r] = fast_exp2(__builtin_fmaf(v, SCALE2, -CSHIFT));
                }
            // P store [q][key] swizzled: logical chunk 2ki+(quad>>1)
            int prow = lrow * 64;
#pragma unroll
            for (int ki = 0; ki < 4; ki++) {
                uint2 w2;
                w2.x = pack_bf16(sv[ki * 4 + 0], sv[ki * 4 + 1]);
                w2.y = pack_bf16(sv[ki * 4 + 2], sv[ki * 4 + 3]);
                int pc = ((ki * 2 + (quad >> 1)) ^ swz) * 8 + (quad & 1) * 4;
                *(uint2*)&Pw[prow + pc] = w2;
            }

            // ---- O^T += V^T P^T ----  (Pw wave-private, DS in-order: no barrier)
            bfrag pf0 = ld_frag(&Pw[prow + ca]);
            bfrag pf1 = ld_frag(&Pw[prow + cb]);
            // l row-sum on the matrix pipe (replaces rsum chain)
            acc_l = __builtin_amdgcn_mfma_f32_16x16x32_bf16(onef, pf0, acc_l, 0, 0, 0);
            acc_l = __builtin_amdgcn_mfma_f32_16x16x32_bf16(onef, pf1, acc_l, 0, 0, 0);
#pragma unroll
            for (int di = 0; di < 4; di++) {
                int vrow = buf + (di * 16 + lrow) * 64;
                bfrag va = ld_frag(&Vs[vrow + ca]);
                bfrag vb = ld_frag(&Vs[vrow + cb]);
                acc[di] = __builtin_amdgcn_mfma_f32_16x16x32_bf16(va, pf0, acc[di], 0, 0, 0);
                acc[di] = __builtin_amdgcn_mfma_f32_16x16x32_bf16(vb, pf1, acc[di], 0, 0, 0);
            }
        }

        // epilogue: transpose O^T -> O via wave-private LDS, coalesced 16B stores.
        // stride 64 (8-way conflict on the 2 reads — negligible, once per phase).
        float rl = __builtin_amdgcn_rcpf(acc_l[0]);  // all rows equal; lane lrow=q
#pragma unroll
        for (int di = 0; di < 4; di++) {
            uint2 w2;
            w2.x = pack_bf16(acc[di][0] * rl, acc[di][1] * rl);
            w2.y = pack_bf16(acc[di][2] * rl, acc[di][3] * rl);
            *(uint2*)&Pw[lrow * 64 + di * 16 + quad * 4] = w2;
        }
        int ql = lane >> 3, cc = lane & 7;
#pragma unroll
        for (int p = 0; p < 2; p++) {
            uint4 vv = *(uint4*)&Pw[(p * 8 + ql) * 64 + cc * 8];
            int q = qw + p * 8 + ql;
            *(uint4*)(ctxb + ((size_t)b * S_LEN + q) * D_MODEL + h * HDIM + cc * 8) = vv;
        }
    }
}

extern "C" void kernel_launch(void* const* d_in, const int* in_sizes, int n_in,
                              void* d_out, int out_size, void* d_ws, size_t ws_size,
                              hipStream_t stream) {
    const float* x   = (const float*)d_in[0];
    const float* W_q = (const float*)d_in[1];
    const float* W_k = (const float*)d_in[2];
    const float* W_v = (const float*)d_in[3];
    const float* W_o = (const float*)d_in[4];
    const float* b_o = (const float*)d_in[5];
    float* out = (float*)d_out;

    // workspace carve (elems, ushort).  Vb (row-layout V) aliases ctxb:
    // Vb is dead after transpose_v, before attn writes ctxb.
    unsigned short* xb   = (unsigned short*)d_ws;                    // 8192*1024
    unsigned short* Wt   = xb + (size_t)8192 * 1024;                 // 4*1024*1024
    unsigned short* Qb   = Wt + (size_t)4 * 1024 * 1024;             // 64*2048*64
    unsigned short* Kb   = Qb + (size_t)64 * 2048 * 64;
    unsigned short* Vtb  = Kb + (size_t)64 * 2048 * 64;
    unsigned short* ctxb = Vtb + (size_t)64 * 2048 * 64;             // 8192*1024
    unsigned short* Vb   = ctxb;
    unsigned short* Wto  = Wt + (size_t)3 * 1024 * 1024;

    // fused cast + weight transpose (one launch)
    prep_kernel<<<8192, 256, 0, stream>>>(x, W_q, W_k, W_v, W_o, xb, Wt);
    // QKV: M=8192, N=3072 (V written row-layout [s][d])
    gemm_kernel<<<dim3(24, 64), 256, 0, stream>>>(xb, Wt, 0, Qb, Kb, Vb, nullptr, nullptr);
    // V transpose [s][d] -> [d][s]
    transpose_v_kernel<<<dim3(32, 64), 256, 0, stream>>>(Vb, Vtb);
    // attention (split-q: block bx does 64-row chunks 31-bx then bx; 33 tiles each)
    attn_kernel<<<dim3(16, 64), 256, 0, stream>>>(Qb, Kb, Vtb, ctxb);
    // out proj: M=8192, N=1024, + bias
    gemm_kernel<<<dim3(8, 64), 256, 0, stream>>>(ctxb, Wto, 1, nullptr, nullptr, nullptr, out, b_o);
}